// Round 12
// baseline (80.684 us; speedup 1.0000x reference)
//
#include <hip/hip_runtime.h>
#include <math.h>

#define NN 8192
#define DD 512
#define MM 4
#define EE 131072
#define NB 4    // 16-pair batches per wave; 1024 blocks x 4 waves x 4 x 16 = 262144

typedef float  floatx2 __attribute__((ext_vector_type(2)));
typedef _Float16 h2    __attribute__((ext_vector_type(2)));
typedef _Float16 f16x8 __attribute__((ext_vector_type(8)));
typedef float  f32x4   __attribute__((ext_vector_type(4)));

union F8U { f16x8 v; h2 h[4]; uint2 u2[2]; };

__device__ inline h2 pkrtz(float a, float b) {
    return __builtin_bit_cast(h2, __builtin_amdgcn_cvt_pkrtz(a, b));
}

__device__ inline float fdot2a(h2 a, h2 b, float c) {
#if __has_builtin(__builtin_amdgcn_fdot2)
    return __builtin_amdgcn_fdot2(a, b, c, false);
#else
    return c + (float)a[0] * (float)b[0] + (float)a[1] * (float)b[1];
#endif
}

// Dequant 8 fp8 e4m3 (uint2) -> f16x8. Exact (e4m3 subset of f16).
__device__ inline f16x8 deq8v(uint2 u) {
    F8U o;
    floatx2 f;
    f = __builtin_amdgcn_cvt_pk_f32_fp8((int)u.x, false); o.h[0] = pkrtz(f[0], f[1]);
    f = __builtin_amdgcn_cvt_pk_f32_fp8((int)u.x, true);  o.h[1] = pkrtz(f[0], f[1]);
    f = __builtin_amdgcn_cvt_pk_f32_fp8((int)u.y, false); o.h[2] = pkrtz(f[0], f[1]);
    f = __builtin_amdgcn_cvt_pk_f32_fp8((int)u.y, true);  o.h[3] = pkrtz(f[0], f[1]);
    return o.v;
}

template <int CTRL>
__device__ inline float dpp_add(float v) {
    int x = __builtin_amdgcn_update_dpp(0, __builtin_bit_cast(int, v), CTRL, 0xf, 0xf, true);
    return v + __builtin_bit_cast(float, x);
}

// ---------------------------------------------------------------------------
// Kernel 1 (r9/r11-verified, unchanged): fp8 e4m3 row-linear table + recip
// norms from the SAME dequantized f16 values. rn transposed rn_t[m][n].
// ---------------------------------------------------------------------------
__global__ __launch_bounds__(256) void quant_norm_kernel(const float* __restrict__ emb,
                                                         const float* __restrict__ mh,
                                                         uint2* __restrict__ q,
                                                         float* __restrict__ rn_t,
                                                         float* __restrict__ out) {
    if (blockIdx.x == 0 && threadIdx.x == 0) out[0] = 0.0f;

    const int lane = threadIdx.x & 63;
    const unsigned n = blockIdx.x * 4 + (threadIdx.x >> 6);

    const float* er = emb + n * DD + lane * 8;
    float4 e0 = *(const float4*)(er);
    float4 e1 = *(const float4*)(er + 4);

    int lo = 0, hi = 0;
    lo = __builtin_amdgcn_cvt_pk_fp8_f32(e0.x, e0.y, lo, false);
    lo = __builtin_amdgcn_cvt_pk_fp8_f32(e0.z, e0.w, lo, true);
    hi = __builtin_amdgcn_cvt_pk_fp8_f32(e1.x, e1.y, hi, false);
    hi = __builtin_amdgcn_cvt_pk_fp8_f32(e1.z, e1.w, hi, true);

    uint2 u = make_uint2((unsigned)lo, (unsigned)hi);
    q[(n << 6) | lane] = u;

    F8U A; A.v = deq8v(u);
    h2 p0 = A.h[0] * A.h[0];
    h2 p1 = A.h[1] * A.h[1];
    h2 p2 = A.h[2] * A.h[2];
    h2 p3 = A.h[3] * A.h[3];

    const float* mb = mh + lane * 8;
    float ss[4];
    #pragma unroll
    for (int m = 0; m < 4; ++m) {
        float4 m0 = *(const float4*)(mb + m * DD);
        float4 m1 = *(const float4*)(mb + m * DD + 4);
        h2 w0 = pkrtz(m0.x * m0.x, m0.y * m0.y);
        h2 w1 = pkrtz(m0.z * m0.z, m0.w * m0.w);
        h2 w2 = pkrtz(m1.x * m1.x, m1.y * m1.y);
        h2 w3 = pkrtz(m1.z * m1.z, m1.w * m1.w);
        float s = 0.f;
        s = fdot2a(p0, w0, s);
        s = fdot2a(p1, w1, s);
        s = fdot2a(p2, w2, s);
        s = fdot2a(p3, w3, s);
        ss[m] = s;
    }

    ss[0] = dpp_add<0x111>(ss[0]); ss[1] = dpp_add<0x111>(ss[1]);
    ss[2] = dpp_add<0x111>(ss[2]); ss[3] = dpp_add<0x111>(ss[3]);
    ss[0] = dpp_add<0x112>(ss[0]); ss[1] = dpp_add<0x112>(ss[1]);
    ss[2] = dpp_add<0x112>(ss[2]); ss[3] = dpp_add<0x112>(ss[3]);
    ss[0] = dpp_add<0x114>(ss[0]); ss[1] = dpp_add<0x114>(ss[1]);
    ss[2] = dpp_add<0x114>(ss[2]); ss[3] = dpp_add<0x114>(ss[3]);
    ss[0] = dpp_add<0x118>(ss[0]); ss[1] = dpp_add<0x118>(ss[1]);
    ss[2] = dpp_add<0x118>(ss[2]); ss[3] = dpp_add<0x118>(ss[3]);
    ss[0] = dpp_add<0x142>(ss[0]); ss[1] = dpp_add<0x142>(ss[1]);
    ss[2] = dpp_add<0x142>(ss[2]); ss[3] = dpp_add<0x142>(ss[3]);
    ss[0] = dpp_add<0x143>(ss[0]); ss[1] = dpp_add<0x143>(ss[1]);
    ss[2] = dpp_add<0x143>(ss[2]); ss[3] = dpp_add<0x143>(ss[3]);

    if (lane == 63) {
        rn_t[0 * NN + n] = 1.0f / fmaxf(sqrtf(ss[0]), 1e-12f);
        rn_t[1 * NN + n] = 1.0f / fmaxf(sqrtf(ss[1]), 1e-12f);
        rn_t[2 * NN + n] = 1.0f / fmaxf(sqrtf(ss[2]), 1e-12f);
        rn_t[3 * NN + n] = 1.0f / fmaxf(sqrtf(ss[3]), 1e-12f);
    }
}

// ---------------------------------------------------------------------------
// Kernel 2: MFMA + k-phase-split LDS product-transpose (8 KB/wave).
//  - per batch: 64 up-front 4B gathers (2 chunks x 2 sides x 16 pairs),
//    each 256B-coalesced; phase-1 chunks fly during phase-0 compute
//  - phase kp (256 dims): products (f16x4/lane) -> ds_write_b64 at
//    s*512 + ((lane*8) ^ ((s&7)<<4)); fragment ds_read_b128 at
//    p*512 + ((mf*64+kq*16) ^ ((p&7)<<4)); 8 MFMAs/phase, acc across phases
//  - B-weights in LDS, r8-verified layout; epilogue r8-verified
// ---------------------------------------------------------------------------
__global__ __launch_bounds__(256) void pair_kernel(const int* __restrict__ edges,
                                                   const int* __restrict__ nedges,
                                                   const unsigned char* __restrict__ qtab,
                                                   const float* __restrict__ mh,
                                                   const float* __restrict__ rn_t,
                                                   float* __restrict__ out) {
    __shared__ __align__(16) unsigned char stage[4][8192];   // 32 KiB
    __shared__ _Float16 wlds[2048];                          // 4 KiB

    const int t = threadIdx.x;
    {   // stage squared f16 weights (r8-verified layout)
        int m = t >> 6, sl = t & 63;
        const float* mb = mh + m * DD + sl * 8;
        float4 m0 = *(const float4*)(mb);
        float4 m1 = *(const float4*)(mb + 4);
        F8U wv;
        wv.h[0] = pkrtz(m0.x * m0.x, m0.y * m0.y);
        wv.h[1] = pkrtz(m0.z * m0.z, m0.w * m0.w);
        wv.h[2] = pkrtz(m1.x * m1.x, m1.y * m1.y);
        wv.h[3] = pkrtz(m1.z * m1.z, m1.w * m1.w);
        int s = (sl >> 2) * 16 + (sl & 3) * 4 + m;   // kk*16 + kq*4 + m
        *(f16x8*)(&wlds[s * 8]) = wv.v;
    }
    __syncthreads();

    const int lane   = t & 63;
    const int waveId = t >> 6;
    const int p  = lane & 15;     // pair-row / B-col
    const int kq = lane >> 4;     // k-quad
    const int m  = p & 3;

    unsigned char* wp = stage[waveId];
    const _Float16* wbase = &wlds[(kq * 4 + m) * 8];
    const float*    rm    = rn_t + m * NN;

    const int gw   = blockIdx.x * 4 + waveId;     // 4096 waves x 64 pairs
    const int base = gw * (NB * 16);
    const bool pos = base < EE;
    const int* eb  = pos ? edges : nedges;
    const int  lb  = pos ? base : base - EE;

    const unsigned swz_w = (unsigned)(lane * 8);
    const unsigned c0 = (unsigned)(lane * 4);
    const unsigned c1 = (unsigned)(256 + lane * 4);

    float lsum = 0.f;

    #pragma unroll 1
    for (int bt = 0; bt < NB; ++bt) {
        const int lb2 = lb + bt * 16;

        // ---- all 64 gathers up-front (phase-1 overlaps phase-0 compute) ----
        unsigned ga0[16], ga1[16], gb0[16], gb1[16];
        #pragma unroll
        for (int s = 0; s < 16; ++s) {
            int is = eb[lb2 + s];          // wave-uniform
            int js = eb[lb2 + EE + s];
            const unsigned char* qi = qtab + ((size_t)(unsigned)is << 9);
            const unsigned char* qj = qtab + ((size_t)(unsigned)js << 9);
            ga0[s] = *(const unsigned*)(qi + c0);
            ga1[s] = *(const unsigned*)(qi + c1);
            gb0[s] = *(const unsigned*)(qj + c0);
            gb1[s] = *(const unsigned*)(qj + c1);
        }

        // epilogue operands (overlap with compute)
        int4 pi4 = *(const int4*)(eb + lb2 + kq * 4);
        int4 pj4 = *(const int4*)(eb + lb2 + EE + kq * 4);
        float w0 = rm[pi4.x] * rm[pj4.x];
        float w1 = rm[pi4.y] * rm[pj4.y];
        float w2 = rm[pi4.z] * rm[pj4.z];
        float w3 = rm[pi4.w] * rm[pj4.w];

        f32x4 acc0 = {0.f, 0.f, 0.f, 0.f};
        f32x4 acc1 = {0.f, 0.f, 0.f, 0.f};

        #pragma unroll
        for (int kp = 0; kp < 2; ++kp) {
            // ---- products -> LDS (write side of swizzle) ----
            #pragma unroll
            for (int s = 0; s < 16; ++s) {
                unsigned ua = kp ? ga1[s] : ga0[s];
                unsigned ub = kp ? gb1[s] : gb0[s];
                floatx2 fa0 = __builtin_amdgcn_cvt_pk_f32_fp8((int)ua, false);
                floatx2 fa1 = __builtin_amdgcn_cvt_pk_f32_fp8((int)ua, true);
                floatx2 fb0 = __builtin_amdgcn_cvt_pk_f32_fp8((int)ub, false);
                floatx2 fb1 = __builtin_amdgcn_cvt_pk_f32_fp8((int)ub, true);
                h2 pr0 = pkrtz(fa0[0], fa0[1]) * pkrtz(fb0[0], fb0[1]);
                h2 pr1 = pkrtz(fa1[0], fa1[1]) * pkrtz(fb1[0], fb1[1]);
                unsigned off = (unsigned)(s * 512) + (swz_w ^ ((unsigned)(s & 7) << 4));
                *(uint2*)(&wp[off]) = make_uint2(__builtin_bit_cast(unsigned, pr0),
                                                 __builtin_bit_cast(unsigned, pr1));
            }

            // ---- fragment reads + MFMA (read side of swizzle) ----
            #pragma unroll
            for (int mf = 0; mf < 8; mf += 2) {
                unsigned ro0 = (unsigned)(p * 512) +
                               ((unsigned)(mf * 64 + kq * 16) ^ ((unsigned)(p & 7) << 4));
                f16x8 av0 = *(const f16x8*)(&wp[ro0]);
                acc0 = __builtin_amdgcn_mfma_f32_16x16x32_f16(
                           av0, *(const f16x8*)(wbase + (kp * 8 + mf) * 128), acc0, 0, 0, 0);
                unsigned ro1 = (unsigned)(p * 512) +
                               ((unsigned)((mf + 1) * 64 + kq * 16) ^ ((unsigned)(p & 7) << 4));
                f16x8 av1 = *(const f16x8*)(&wp[ro1]);
                acc1 = __builtin_amdgcn_mfma_f32_16x16x32_f16(
                           av1, *(const f16x8*)(wbase + (kp * 8 + mf + 1) * 128), acc1, 0, 0, 0);
            }
        }

        // ---- epilogue (r8-verified mapping) ----
        float v0 = (acc0[0] + acc1[0]) * w0;
        float v1 = (acc0[1] + acc1[1]) * w1;
        float v2 = (acc0[2] + acc1[2]) * w2;
        float v3 = (acc0[3] + acc1[3]) * w3;
        v0 = dpp_add<0x111>(v0); v1 = dpp_add<0x111>(v1);
        v2 = dpp_add<0x111>(v2); v3 = dpp_add<0x111>(v3);
        v0 = dpp_add<0x112>(v0); v1 = dpp_add<0x112>(v1);
        v2 = dpp_add<0x112>(v2); v3 = dpp_add<0x112>(v3);
        // lane p==3 (per kq row) holds full m-sums for pairs kq*4 + 0..3

        float d0 = 1.000001f - 0.25f * v0;
        float d1 = 1.000001f - 0.25f * v1;
        float d2 = 1.000001f - 0.25f * v2;
        float d3 = 1.000001f - 0.25f * v3;
        float a0 = pos ? d0 : fmaf(-0.5f, d0, 1.0f);
        float a1 = pos ? d1 : fmaf(-0.5f, d1, 1.0f);
        float a2 = pos ? d2 : fmaf(-0.5f, d2, 1.0f);
        float a3 = pos ? d3 : fmaf(-0.5f, d3, 1.0f);
        float lg = __logf(fmaxf(a0, 1e-8f)) + __logf(fmaxf(a1, 1e-8f)) +
                   __logf(fmaxf(a2, 1e-8f)) + __logf(fmaxf(a3, 1e-8f));
        lsum += (p == 3) ? lg : 0.f;
    }

    // final 64-lane reduce (nonzero only in lanes 3,19,35,51)
    lsum = dpp_add<0x111>(lsum);
    lsum = dpp_add<0x112>(lsum);
    lsum = dpp_add<0x114>(lsum);
    lsum = dpp_add<0x118>(lsum);
    lsum = dpp_add<0x142>(lsum);
    lsum = dpp_add<0x143>(lsum);

    if (lane == 63) atomicAdd(out, -lsum);
}

extern "C" void kernel_launch(void* const* d_in, const int* in_sizes, int n_in,
                              void* d_out, int out_size, void* d_ws, size_t ws_size,
                              hipStream_t stream) {
    const int*   edges  = (const int*)d_in[0];
    const int*   nedges = (const int*)d_in[1];
    const float* emb    = (const float*)d_in[2];
    const float* mh     = (const float*)d_in[3];
    float* out = (float*)d_out;

    uint2* q    = (uint2*)d_ws;                                  // 4 MiB fp8 table
    float* rn_t = (float*)((char*)d_ws + (size_t)NN * DD);       // 128 KiB, [m][n]

    quant_norm_kernel<<<NN / 4, 256, 0, stream>>>(emb, mh, q, rn_t, out);
    pair_kernel<<<(2 * EE) / (4 * NB * 16), 256, 0, stream>>>(edges, nedges,
                                                              (const unsigned char*)q,
                                                              mh, rn_t, out);
}

// Round 13
// 79.538 us; speedup vs baseline: 1.0144x; 1.0144x over previous
//
#include <hip/hip_runtime.h>
#include <math.h>

#define NN 8192
#define DD 512
#define MM 4
#define EE 131072

typedef float  floatx2 __attribute__((ext_vector_type(2)));
typedef _Float16 h2    __attribute__((ext_vector_type(2)));

__device__ inline h2 pkrtz(float a, float b) {
    return __builtin_bit_cast(h2, __builtin_amdgcn_cvt_pkrtz(a, b));
}

__device__ inline float fdot2a(h2 a, h2 b, float c) {
#if __has_builtin(__builtin_amdgcn_fdot2)
    return __builtin_amdgcn_fdot2(a, b, c, false);
#else
    return c + (float)a[0] * (float)b[0] + (float)a[1] * (float)b[1];
#endif
}

template <int CTRL>
__device__ inline float dpp_add(float v) {
    int x = __builtin_amdgcn_update_dpp(0, __builtin_bit_cast(int, v), CTRL, 0xf, 0xf, true);
    return v + __builtin_bit_cast(float, x);
}

// ---------------------------------------------------------------------------
// Kernel 1 (r7-verified numerics): fp8 e4m3 row-linear table + reciprocal
// norms from the SAME dequantized h2 values / fdot2 chain the pair kernel
// uses (self-pairs exact). rn[n] stored as float4. Zeroes out[0].
// ---------------------------------------------------------------------------
__global__ __launch_bounds__(256) void quant_norm_kernel(const float* __restrict__ emb,
                                                         const float* __restrict__ mh,
                                                         uint2* __restrict__ q,
                                                         float* __restrict__ rn,
                                                         float* __restrict__ out) {
    if (blockIdx.x == 0 && threadIdx.x == 0) out[0] = 0.0f;

    const int lane = threadIdx.x & 63;
    const unsigned n = blockIdx.x * 4 + (threadIdx.x >> 6);

    const float* er = emb + n * DD + lane * 8;
    float4 e0 = *(const float4*)(er);
    float4 e1 = *(const float4*)(er + 4);

    int lo = 0, hi = 0;
    lo = __builtin_amdgcn_cvt_pk_fp8_f32(e0.x, e0.y, lo, false);
    lo = __builtin_amdgcn_cvt_pk_fp8_f32(e0.z, e0.w, lo, true);
    hi = __builtin_amdgcn_cvt_pk_fp8_f32(e1.x, e1.y, hi, false);
    hi = __builtin_amdgcn_cvt_pk_fp8_f32(e1.z, e1.w, hi, true);

    uint2 u = make_uint2((unsigned)lo, (unsigned)hi);
    q[(n << 6) | lane] = u;

    floatx2 f;
    h2 A0, A1, A2, A3;
    f = __builtin_amdgcn_cvt_pk_f32_fp8((int)u.x, false); A0 = pkrtz(f[0], f[1]);
    f = __builtin_amdgcn_cvt_pk_f32_fp8((int)u.x, true);  A1 = pkrtz(f[0], f[1]);
    f = __builtin_amdgcn_cvt_pk_f32_fp8((int)u.y, false); A2 = pkrtz(f[0], f[1]);
    f = __builtin_amdgcn_cvt_pk_f32_fp8((int)u.y, true);  A3 = pkrtz(f[0], f[1]);
    h2 p0 = A0 * A0;
    h2 p1 = A1 * A1;
    h2 p2 = A2 * A2;
    h2 p3 = A3 * A3;

    const float* mb = mh + lane * 8;
    float ss[4];
    #pragma unroll
    for (int m = 0; m < 4; ++m) {
        float4 m0 = *(const float4*)(mb + m * DD);
        float4 m1 = *(const float4*)(mb + m * DD + 4);
        h2 w0 = pkrtz(m0.x * m0.x, m0.y * m0.y);
        h2 w1 = pkrtz(m0.z * m0.z, m0.w * m0.w);
        h2 w2 = pkrtz(m1.x * m1.x, m1.y * m1.y);
        h2 w3 = pkrtz(m1.z * m1.z, m1.w * m1.w);
        float s = 0.f;
        s = fdot2a(p0, w0, s);
        s = fdot2a(p1, w1, s);
        s = fdot2a(p2, w2, s);
        s = fdot2a(p3, w3, s);
        ss[m] = s;
    }

    ss[0] = dpp_add<0x111>(ss[0]); ss[1] = dpp_add<0x111>(ss[1]);
    ss[2] = dpp_add<0x111>(ss[2]); ss[3] = dpp_add<0x111>(ss[3]);
    ss[0] = dpp_add<0x112>(ss[0]); ss[1] = dpp_add<0x112>(ss[1]);
    ss[2] = dpp_add<0x112>(ss[2]); ss[3] = dpp_add<0x112>(ss[3]);
    ss[0] = dpp_add<0x114>(ss[0]); ss[1] = dpp_add<0x114>(ss[1]);
    ss[2] = dpp_add<0x114>(ss[2]); ss[3] = dpp_add<0x114>(ss[3]);
    ss[0] = dpp_add<0x118>(ss[0]); ss[1] = dpp_add<0x118>(ss[1]);
    ss[2] = dpp_add<0x118>(ss[2]); ss[3] = dpp_add<0x118>(ss[3]);
    ss[0] = dpp_add<0x142>(ss[0]); ss[1] = dpp_add<0x142>(ss[1]);
    ss[2] = dpp_add<0x142>(ss[2]); ss[3] = dpp_add<0x142>(ss[3]);
    ss[0] = dpp_add<0x143>(ss[0]); ss[1] = dpp_add<0x143>(ss[1]);
    ss[2] = dpp_add<0x143>(ss[2]); ss[3] = dpp_add<0x143>(ss[3]);

    if (lane == 63) {
        float4 r;
        r.x = 1.0f / fmaxf(sqrtf(ss[0]), 1e-12f);
        r.y = 1.0f / fmaxf(sqrtf(ss[1]), 1e-12f);
        r.z = 1.0f / fmaxf(sqrtf(ss[2]), 1e-12f);
        r.w = 1.0f / fmaxf(sqrtf(ss[3]), 1e-12f);
        *(float4*)(rn + (n << 2)) = r;
    }
}

// ---------------------------------------------------------------------------
// Kernel 2: r7 VALU core, 64 pairs/wave as 8 stages of 8 pairs, explicit
// depth-2 register pipeline (stage t+1's 16 row-gathers + rn products in
// flight while stage t computes ~340 VALU ops).
// ---------------------------------------------------------------------------
struct Stage8 {
    uint2  qa[8], qb[8];   // row data, lane = dim-slice (8 dims/lane)
    float4 rw[8];          // per-pair rn_i[m]*rn_j[m]
};

__device__ inline void load_stage(Stage8& S, const int* __restrict__ eb, int pb,
                                  const uint2* __restrict__ q,
                                  const float* __restrict__ rn, int lane) {
    int4 iv0 = *(const int4*)(eb + pb);
    int4 iv1 = *(const int4*)(eb + pb + 4);
    int4 jv0 = *(const int4*)(eb + EE + pb);
    int4 jv1 = *(const int4*)(eb + EE + pb + 4);

    S.qa[0] = q[((unsigned)iv0.x << 6) | lane];
    S.qb[0] = q[((unsigned)jv0.x << 6) | lane];
    S.qa[1] = q[((unsigned)iv0.y << 6) | lane];
    S.qb[1] = q[((unsigned)jv0.y << 6) | lane];
    S.qa[2] = q[((unsigned)iv0.z << 6) | lane];
    S.qb[2] = q[((unsigned)jv0.z << 6) | lane];
    S.qa[3] = q[((unsigned)iv0.w << 6) | lane];
    S.qb[3] = q[((unsigned)jv0.w << 6) | lane];
    S.qa[4] = q[((unsigned)iv1.x << 6) | lane];
    S.qb[4] = q[((unsigned)jv1.x << 6) | lane];
    S.qa[5] = q[((unsigned)iv1.y << 6) | lane];
    S.qb[5] = q[((unsigned)jv1.y << 6) | lane];
    S.qa[6] = q[((unsigned)iv1.z << 6) | lane];
    S.qb[6] = q[((unsigned)jv1.z << 6) | lane];
    S.qa[7] = q[((unsigned)iv1.w << 6) | lane];
    S.qb[7] = q[((unsigned)jv1.w << 6) | lane];

    int ii[8] = {iv0.x, iv0.y, iv0.z, iv0.w, iv1.x, iv1.y, iv1.z, iv1.w};
    int jj[8] = {jv0.x, jv0.y, jv0.z, jv0.w, jv1.x, jv1.y, jv1.z, jv1.w};
    #pragma unroll
    for (int s = 0; s < 8; ++s) {
        float4 ri = *(const float4*)(rn + ((unsigned)ii[s] << 2));
        float4 rj = *(const float4*)(rn + ((unsigned)jj[s] << 2));
        S.rw[s].x = ri.x * rj.x;
        S.rw[s].y = ri.y * rj.y;
        S.rw[s].z = ri.z * rj.z;
        S.rw[s].w = ri.w * rj.w;
    }
}

__device__ inline float pair_dot(uint2 ua, uint2 ub, const h2 w[4][4], float4 rw) {
    floatx2 f;
    h2 A0, A1, A2, A3, B0, B1, B2, B3;
    f = __builtin_amdgcn_cvt_pk_f32_fp8((int)ua.x, false); A0 = pkrtz(f[0], f[1]);
    f = __builtin_amdgcn_cvt_pk_f32_fp8((int)ua.x, true);  A1 = pkrtz(f[0], f[1]);
    f = __builtin_amdgcn_cvt_pk_f32_fp8((int)ua.y, false); A2 = pkrtz(f[0], f[1]);
    f = __builtin_amdgcn_cvt_pk_f32_fp8((int)ua.y, true);  A3 = pkrtz(f[0], f[1]);
    f = __builtin_amdgcn_cvt_pk_f32_fp8((int)ub.x, false); B0 = pkrtz(f[0], f[1]);
    f = __builtin_amdgcn_cvt_pk_f32_fp8((int)ub.x, true);  B1 = pkrtz(f[0], f[1]);
    f = __builtin_amdgcn_cvt_pk_f32_fp8((int)ub.y, false); B2 = pkrtz(f[0], f[1]);
    f = __builtin_amdgcn_cvt_pk_f32_fp8((int)ub.y, true);  B3 = pkrtz(f[0], f[1]);
    h2 p0 = A0 * B0;
    h2 p1 = A1 * B1;
    h2 p2 = A2 * B2;
    h2 p3 = A3 * B3;

    float a0 = 0.f, a1 = 0.f, a2 = 0.f, a3 = 0.f;
    a0 = fdot2a(p0, w[0][0], a0); a0 = fdot2a(p1, w[0][1], a0);
    a0 = fdot2a(p2, w[0][2], a0); a0 = fdot2a(p3, w[0][3], a0);
    a1 = fdot2a(p0, w[1][0], a1); a1 = fdot2a(p1, w[1][1], a1);
    a1 = fdot2a(p2, w[1][2], a1); a1 = fdot2a(p3, w[1][3], a1);
    a2 = fdot2a(p0, w[2][0], a2); a2 = fdot2a(p1, w[2][1], a2);
    a2 = fdot2a(p2, w[2][2], a2); a2 = fdot2a(p3, w[2][3], a2);
    a3 = fdot2a(p0, w[3][0], a3); a3 = fdot2a(p1, w[3][1], a3);
    a3 = fdot2a(p2, w[3][2], a3); a3 = fdot2a(p3, w[3][3], a3);

    float v = a0 * rw.x;
    v = fmaf(a1, rw.y, v);
    v = fmaf(a2, rw.z, v);
    v = fmaf(a3, rw.w, v);
    return v;
}

__device__ inline float proc_stage(const Stage8& S, const h2 w[4][4], bool pos) {
    float v[8];
    #pragma unroll
    for (int s = 0; s < 8; ++s)
        v[s] = pair_dot(S.qa[s], S.qb[s], w, S.rw[s]);

    #pragma unroll
    for (int s = 0; s < 8; ++s) v[s] = dpp_add<0x111>(v[s]);
    #pragma unroll
    for (int s = 0; s < 8; ++s) v[s] = dpp_add<0x112>(v[s]);
    #pragma unroll
    for (int s = 0; s < 8; ++s) v[s] = dpp_add<0x114>(v[s]);
    #pragma unroll
    for (int s = 0; s < 8; ++s) v[s] = dpp_add<0x118>(v[s]);
    #pragma unroll
    for (int s = 0; s < 8; ++s) v[s] = dpp_add<0x142>(v[s]);
    #pragma unroll
    for (int s = 0; s < 8; ++s) v[s] = dpp_add<0x143>(v[s]);

    float lg = 0.f;
    #pragma unroll
    for (int s = 0; s < 8; ++s) {
        float d = 1.000001f - 0.25f * v[s];
        float a = pos ? d : fmaf(-0.5f, d, 1.0f);
        lg += __logf(fmaxf(a, 1e-8f));
    }
    return lg;
}

__global__ __launch_bounds__(256) void pair_kernel(const int* __restrict__ edges,
                                                   const int* __restrict__ nedges,
                                                   const uint2* __restrict__ q,
                                                   const float* __restrict__ mh,
                                                   const float* __restrict__ rn,
                                                   float* __restrict__ out) {
    const int lane   = threadIdx.x & 63;
    const int waveId = threadIdx.x >> 6;
    const int gw     = blockIdx.x * 4 + waveId;   // 4096 waves x 64 pairs

    // Per-lane f16 weights (r7-verified): w[m][k] = f16(mh[m][lane*8+2k..+1]^2)
    const float* mb = mh + lane * 8;
    h2 w[4][4];
    #pragma unroll
    for (int m = 0; m < 4; ++m) {
        float4 m0 = *(const float4*)(mb + m * DD);
        float4 m1 = *(const float4*)(mb + m * DD + 4);
        w[m][0] = pkrtz(m0.x * m0.x, m0.y * m0.y);
        w[m][1] = pkrtz(m0.z * m0.z, m0.w * m0.w);
        w[m][2] = pkrtz(m1.x * m1.x, m1.y * m1.y);
        w[m][3] = pkrtz(m1.z * m1.z, m1.w * m1.w);
    }

    const int  base = gw * 64;
    const bool pos  = (base < EE);
    const int* eb   = pos ? edges : nedges;
    const int  lb   = pos ? base : base - EE;

    float sum = 0.f;
    Stage8 SA, SB;

    load_stage(SA, eb, lb,      q, rn, lane);
    load_stage(SB, eb, lb + 8,  q, rn, lane);
    sum += proc_stage(SA, w, pos);
    load_stage(SA, eb, lb + 16, q, rn, lane);
    sum += proc_stage(SB, w, pos);
    load_stage(SB, eb, lb + 24, q, rn, lane);
    sum += proc_stage(SA, w, pos);
    load_stage(SA, eb, lb + 32, q, rn, lane);
    sum += proc_stage(SB, w, pos);
    load_stage(SB, eb, lb + 40, q, rn, lane);
    sum += proc_stage(SA, w, pos);
    load_stage(SA, eb, lb + 48, q, rn, lane);
    sum += proc_stage(SB, w, pos);
    load_stage(SB, eb, lb + 56, q, rn, lane);
    sum += proc_stage(SA, w, pos);
    sum += proc_stage(SB, w, pos);

    __shared__ float wsum[4];
    if (lane == 63) wsum[waveId] = sum;
    __syncthreads();
    if (threadIdx.x == 0) {
        float t = wsum[0] + wsum[1] + wsum[2] + wsum[3];
        atomicAdd(out, -t);
    }
}

extern "C" void kernel_launch(void* const* d_in, const int* in_sizes, int n_in,
                              void* d_out, int out_size, void* d_ws, size_t ws_size,
                              hipStream_t stream) {
    const int*   edges  = (const int*)d_in[0];
    const int*   nedges = (const int*)d_in[1];
    const float* emb    = (const float*)d_in[2];
    const float* mh     = (const float*)d_in[3];
    float* out = (float*)d_out;

    uint2* q  = (uint2*)d_ws;                                    // 4 MiB fp8 table
    float* rn = (float*)((char*)d_ws + (size_t)NN * DD);         // 128 KiB float4/node

    quant_norm_kernel<<<NN / 4, 256, 0, stream>>>(emb, mh, q, rn, out);
    pair_kernel<<<(2 * EE) / (4 * 64), 256, 0, stream>>>(edges, nedges, q, mh, rn, out);
}

// Round 14
// 57.679 us; speedup vs baseline: 1.3988x; 1.3790x over previous
//
#include <hip/hip_runtime.h>
#include <math.h>

#define NN 8192
#define DD 512
#define MM 4
#define EE 131072
#define NB 16   // 16-pair block-batches per block; 1024 blocks x 256 pairs

typedef float  floatx2 __attribute__((ext_vector_type(2)));
typedef _Float16 h2    __attribute__((ext_vector_type(2)));
typedef _Float16 f16x8 __attribute__((ext_vector_type(8)));
typedef float  f32x4   __attribute__((ext_vector_type(4)));

union F8U { f16x8 v; h2 h[4]; uint2 u2[2]; };

__device__ inline h2 pkrtz(float a, float b) {
    return __builtin_bit_cast(h2, __builtin_amdgcn_cvt_pkrtz(a, b));
}

__device__ inline float fdot2a(h2 a, h2 b, float c) {
#if __has_builtin(__builtin_amdgcn_fdot2)
    return __builtin_amdgcn_fdot2(a, b, c, false);
#else
    return c + (float)a[0] * (float)b[0] + (float)a[1] * (float)b[1];
#endif
}

// Dequant 8 fp8 e4m3 (uint2) -> f16x8. Exact (e4m3 subset of f16).
__device__ inline f16x8 deq8v(uint2 u) {
    F8U o;
    floatx2 f;
    f = __builtin_amdgcn_cvt_pk_f32_fp8((int)u.x, false); o.h[0] = pkrtz(f[0], f[1]);
    f = __builtin_amdgcn_cvt_pk_f32_fp8((int)u.x, true);  o.h[1] = pkrtz(f[0], f[1]);
    f = __builtin_amdgcn_cvt_pk_f32_fp8((int)u.y, false); o.h[2] = pkrtz(f[0], f[1]);
    f = __builtin_amdgcn_cvt_pk_f32_fp8((int)u.y, true);  o.h[3] = pkrtz(f[0], f[1]);
    return o.v;
}

template <int CTRL>
__device__ inline float dpp_add(float v) {
    int x = __builtin_amdgcn_update_dpp(0, __builtin_bit_cast(int, v), CTRL, 0xf, 0xf, true);
    return v + __builtin_bit_cast(float, x);
}

// Async global->LDS: per-lane global src, uniform LDS base (+lane*16 in HW).
__device__ inline void dma16(const void* g, void* l) {
    __builtin_amdgcn_global_load_lds(
        (const __attribute__((address_space(1))) void*)g,
        (__attribute__((address_space(3))) void*)l, 16, 0, 0);
}

// ---------------------------------------------------------------------------
// Kernel 1 (r8-r12 verified): fp8 e4m3 row-linear table + reciprocal norms
// from the SAME dequantized h2 values. rn TRANSPOSED rn_t[m][n]. Zeroes out.
// ---------------------------------------------------------------------------
__global__ __launch_bounds__(256) void quant_norm_kernel(const float* __restrict__ emb,
                                                         const float* __restrict__ mh,
                                                         uint2* __restrict__ q,
                                                         float* __restrict__ rn_t,
                                                         float* __restrict__ out) {
    if (blockIdx.x == 0 && threadIdx.x == 0) out[0] = 0.0f;

    const int lane = threadIdx.x & 63;
    const unsigned n = blockIdx.x * 4 + (threadIdx.x >> 6);

    const float* er = emb + n * DD + lane * 8;
    float4 e0 = *(const float4*)(er);
    float4 e1 = *(const float4*)(er + 4);

    int lo = 0, hi = 0;
    lo = __builtin_amdgcn_cvt_pk_fp8_f32(e0.x, e0.y, lo, false);
    lo = __builtin_amdgcn_cvt_pk_fp8_f32(e0.z, e0.w, lo, true);
    hi = __builtin_amdgcn_cvt_pk_fp8_f32(e1.x, e1.y, hi, false);
    hi = __builtin_amdgcn_cvt_pk_fp8_f32(e1.z, e1.w, hi, true);

    uint2 u = make_uint2((unsigned)lo, (unsigned)hi);
    q[(n << 6) | lane] = u;

    F8U A; A.v = deq8v(u);
    h2 p0 = A.h[0] * A.h[0];
    h2 p1 = A.h[1] * A.h[1];
    h2 p2 = A.h[2] * A.h[2];
    h2 p3 = A.h[3] * A.h[3];

    const float* mb = mh + lane * 8;
    float ss[4];
    #pragma unroll
    for (int m = 0; m < 4; ++m) {
        float4 m0 = *(const float4*)(mb + m * DD);
        float4 m1 = *(const float4*)(mb + m * DD + 4);
        h2 w0 = pkrtz(m0.x * m0.x, m0.y * m0.y);
        h2 w1 = pkrtz(m0.z * m0.z, m0.w * m0.w);
        h2 w2 = pkrtz(m1.x * m1.x, m1.y * m1.y);
        h2 w3 = pkrtz(m1.z * m1.z, m1.w * m1.w);
        float s = 0.f;
        s = fdot2a(p0, w0, s);
        s = fdot2a(p1, w1, s);
        s = fdot2a(p2, w2, s);
        s = fdot2a(p3, w3, s);
        ss[m] = s;
    }

    ss[0] = dpp_add<0x111>(ss[0]); ss[1] = dpp_add<0x111>(ss[1]);
    ss[2] = dpp_add<0x111>(ss[2]); ss[3] = dpp_add<0x111>(ss[3]);
    ss[0] = dpp_add<0x112>(ss[0]); ss[1] = dpp_add<0x112>(ss[1]);
    ss[2] = dpp_add<0x112>(ss[2]); ss[3] = dpp_add<0x112>(ss[3]);
    ss[0] = dpp_add<0x114>(ss[0]); ss[1] = dpp_add<0x114>(ss[1]);
    ss[2] = dpp_add<0x114>(ss[2]); ss[3] = dpp_add<0x114>(ss[3]);
    ss[0] = dpp_add<0x118>(ss[0]); ss[1] = dpp_add<0x118>(ss[1]);
    ss[2] = dpp_add<0x118>(ss[2]); ss[3] = dpp_add<0x118>(ss[3]);
    ss[0] = dpp_add<0x142>(ss[0]); ss[1] = dpp_add<0x142>(ss[1]);
    ss[2] = dpp_add<0x142>(ss[2]); ss[3] = dpp_add<0x142>(ss[3]);
    ss[0] = dpp_add<0x143>(ss[0]); ss[1] = dpp_add<0x143>(ss[1]);
    ss[2] = dpp_add<0x143>(ss[2]); ss[3] = dpp_add<0x143>(ss[3]);

    if (lane == 63) {
        rn_t[0 * NN + n] = 1.0f / fmaxf(sqrtf(ss[0]), 1e-12f);
        rn_t[1 * NN + n] = 1.0f / fmaxf(sqrtf(ss[1]), 1e-12f);
        rn_t[2 * NN + n] = 1.0f / fmaxf(sqrtf(ss[2]), 1e-12f);
        rn_t[3 * NN + n] = 1.0f / fmaxf(sqrtf(ss[3]), 1e-12f);
    }
}

// ---------------------------------------------------------------------------
// Kernel 2: block-cooperative MFMA. All 4 waves co-process one 16-pair batch;
// wave w owns k-quarter mf=4w..4w+3. DMA staging (1 instr = 1 pair: lanes
// 0-31 row i, 32-63 row j), source chunk pre-swizzled (^pair) so fragment
// ds_read_b64 is conflict-free on linear LDS. Double-buffered, vmcnt(4)
// counted across raw barriers (lgkmcnt-only drain). Partial accs exchanged
// via LDS; wave 0 runs the r8-verified epilogue.
// ---------------------------------------------------------------------------
__global__ __launch_bounds__(256) void pair_kernel(const int* __restrict__ edges,
                                                   const int* __restrict__ nedges,
                                                   const unsigned char* __restrict__ qtab,
                                                   const float* __restrict__ mh,
                                                   const float* __restrict__ rn_t,
                                                   float* __restrict__ out) {
    __shared__ __align__(16) unsigned char sbuf[2][16384];   // 32 KiB
    __shared__ _Float16 wlds[2048];                          // 4 KiB
    __shared__ __align__(16) float xchg[4][64][4];           // 4 KiB

    const int t = threadIdx.x;
    {   // stage squared f16 weights (r8-verified layout: slot kk*16+kq*4+m)
        int m = t >> 6, sl = t & 63;
        const float* mb = mh + m * DD + sl * 8;
        float4 m0 = *(const float4*)(mb);
        float4 m1 = *(const float4*)(mb + 4);
        F8U wv;
        wv.h[0] = pkrtz(m0.x * m0.x, m0.y * m0.y);
        wv.h[1] = pkrtz(m0.z * m0.z, m0.w * m0.w);
        wv.h[2] = pkrtz(m1.x * m1.x, m1.y * m1.y);
        wv.h[3] = pkrtz(m1.z * m1.z, m1.w * m1.w);
        int s = (sl >> 2) * 16 + (sl & 3) * 4 + m;
        *(f16x8*)(&wlds[s * 8]) = wv.v;
    }
    __syncthreads();

    const int lane = t & 63;
    const int w    = t >> 6;      // wave id = k-quarter
    const int p    = lane & 15;   // pair-row / B-col
    const int kq   = lane >> 4;   // k-quad within MFMA
    const int m    = p & 3;

    const _Float16* wbase = &wlds[(kq * 4 + m) * 8];
    const float*    rm    = rn_t + m * NN;

    const int  bbase = blockIdx.x * (NB * 16);
    const bool pos   = bbase < EE;
    const int* eb    = pos ? edges : nedges;
    const int  lb    = pos ? bbase : bbase - EE;

    // prologue: batch 0 DMA (wave w stages pairs 4w..4w+3)
    {
        #pragma unroll
        for (int k = 0; k < 4; ++k) {
            int s = w * 4 + k;
            int is = eb[lb + s];
            int js = eb[lb + EE + s];
            int row = (lane < 32) ? is : js;
            const unsigned char* src = qtab + ((size_t)(unsigned)row << 9)
                                     + (((lane & 31) ^ s) << 4);
            dma16(src, &sbuf[0][s * 1024]);
        }
    }

    float lsum = 0.f;

    #pragma unroll 1
    for (int bt = 0; bt < NB; ++bt) {
        const int lb2 = lb + bt * 16;

        // wave 0: epilogue operands for THIS batch (issued before next DMA)
        float rw0 = 0.f, rw1 = 0.f, rw2 = 0.f, rw3 = 0.f;
        if (w == 0) {
            int4 pi4 = *(const int4*)(eb + lb2 + kq * 4);
            int4 pj4 = *(const int4*)(eb + lb2 + EE + kq * 4);
            rw0 = rm[pi4.x] * rm[pj4.x];
            rw1 = rm[pi4.y] * rm[pj4.y];
            rw2 = rm[pi4.z] * rm[pj4.z];
            rw3 = rm[pi4.w] * rm[pj4.w];
        }

        // next-batch DMA into the other buffer
        if (bt + 1 < NB) {
            const int nlb = lb + (bt + 1) * 16;
            unsigned char* dst = sbuf[(bt + 1) & 1];
            #pragma unroll
            for (int k = 0; k < 4; ++k) {
                int s = w * 4 + k;
                int is = eb[nlb + s];
                int js = eb[nlb + EE + s];
                int row = (lane < 32) ? is : js;
                const unsigned char* src = qtab + ((size_t)(unsigned)row << 9)
                                         + (((lane & 31) ^ s) << 4);
                dma16(src, &dst[s * 1024]);
            }
            asm volatile("s_waitcnt vmcnt(4)" ::: "memory");
        } else {
            asm volatile("s_waitcnt vmcnt(0)" ::: "memory");
        }
        __builtin_amdgcn_sched_barrier(0);
        asm volatile("s_waitcnt lgkmcnt(0)" ::: "memory");
        __builtin_amdgcn_s_barrier();          // batch bt data ready

        // compute: wave w handles mf = 4w .. 4w+3
        const unsigned char* bb = sbuf[bt & 1];
        f32x4 acc = {0.f, 0.f, 0.f, 0.f};
        #pragma unroll
        for (int mq = 0; mq < 4; ++mq) {
            int mf = w * 4 + mq;
            int c  = 2 * mf + (kq >> 1);
            unsigned ioff = (unsigned)(p * 1024 + ((c ^ p) << 4) + (kq & 1) * 8);
            uint2 ua = *(const uint2*)(bb + ioff);
            uint2 ub = *(const uint2*)(bb + ioff + 512);
            F8U pa, pb, pr;
            pa.v = deq8v(ua);
            pb.v = deq8v(ub);
            pr.h[0] = pa.h[0] * pb.h[0];
            pr.h[1] = pa.h[1] * pb.h[1];
            pr.h[2] = pa.h[2] * pb.h[2];
            pr.h[3] = pa.h[3] * pb.h[3];
            acc = __builtin_amdgcn_mfma_f32_16x16x32_f16(
                      pr.v, *(const f16x8*)(wbase + mf * 128), acc, 0, 0, 0);
        }

        // exchange partial accumulators
        xchg[w][lane][0] = acc[0];
        xchg[w][lane][1] = acc[1];
        xchg[w][lane][2] = acc[2];
        xchg[w][lane][3] = acc[3];
        asm volatile("s_waitcnt lgkmcnt(0)" ::: "memory");
        __builtin_amdgcn_s_barrier();          // A: partials visible

        if (w == 0) {
            float4 x0 = *(const float4*)(&xchg[0][lane][0]);
            float4 x1 = *(const float4*)(&xchg[1][lane][0]);
            float4 x2 = *(const float4*)(&xchg[2][lane][0]);
            float4 x3 = *(const float4*)(&xchg[3][lane][0]);
            asm volatile("s_waitcnt lgkmcnt(0)" ::: "memory");
            __builtin_amdgcn_sched_barrier(0);

            float v0 = (x0.x + x1.x + x2.x + x3.x) * rw0;
            float v1 = (x0.y + x1.y + x2.y + x3.y) * rw1;
            float v2 = (x0.z + x1.z + x2.z + x3.z) * rw2;
            float v3 = (x0.w + x1.w + x2.w + x3.w) * rw3;
            v0 = dpp_add<0x111>(v0); v1 = dpp_add<0x111>(v1);
            v2 = dpp_add<0x112>(dpp_add<0x111>(v2));
            v0 = dpp_add<0x112>(v0); v1 = dpp_add<0x112>(v1);
            v3 = dpp_add<0x112>(dpp_add<0x111>(v3));
            // lane p==3 (per kq row) holds full m-sums for pairs kq*4 + 0..3

            float d0 = 1.000001f - 0.25f * v0;
            float d1 = 1.000001f - 0.25f * v1;
            float d2 = 1.000001f - 0.25f * v2;
            float d3 = 1.000001f - 0.25f * v3;
            float a0 = pos ? d0 : fmaf(-0.5f, d0, 1.0f);
            float a1 = pos ? d1 : fmaf(-0.5f, d1, 1.0f);
            float a2 = pos ? d2 : fmaf(-0.5f, d2, 1.0f);
            float a3 = pos ? d3 : fmaf(-0.5f, d3, 1.0f);
            float lg = __logf(fmaxf(a0, 1e-8f)) + __logf(fmaxf(a1, 1e-8f)) +
                       __logf(fmaxf(a2, 1e-8f)) + __logf(fmaxf(a3, 1e-8f));
            lsum += (p == 3) ? lg : 0.f;
        }
        __builtin_amdgcn_s_barrier();          // B: xchg/buf safe to reuse
    }

    if (w == 0) {
        lsum = dpp_add<0x111>(lsum);
        lsum = dpp_add<0x112>(lsum);
        lsum = dpp_add<0x114>(lsum);
        lsum = dpp_add<0x118>(lsum);
        lsum = dpp_add<0x142>(lsum);
        lsum = dpp_add<0x143>(lsum);
        if (lane == 63) atomicAdd(out, -lsum);
    }
}

extern "C" void kernel_launch(void* const* d_in, const int* in_sizes, int n_in,
                              void* d_out, int out_size, void* d_ws, size_t ws_size,
                              hipStream_t stream) {
    const int*   edges  = (const int*)d_in[0];
    const int*   nedges = (const int*)d_in[1];
    const float* emb    = (const float*)d_in[2];
    const float* mh     = (const float*)d_in[3];
    float* out = (float*)d_out;

    uint2* q    = (uint2*)d_ws;                                  // 4 MiB fp8 table
    float* rn_t = (float*)((char*)d_ws + (size_t)NN * DD);       // 128 KiB, [m][n]

    quant_norm_kernel<<<NN / 4, 256, 0, stream>>>(emb, mh, q, rn_t, out);
    pair_kernel<<<(2 * EE) / (NB * 16), 256, 0, stream>>>(edges, nedges,
                                                          (const unsigned char*)q,
                                                          mh, rn_t, out);
}